// Round 2
// baseline (443.567 us; speedup 1.0000x reference)
//
#include <hip/hip_runtime.h>
#include <cstdint>

#define T_TOK 4096
#define HID 2048
#define NH 16
#define NKV 4
#define HD 128
#define WIN 1024
#define QKVO 3072

typedef float f32x4 __attribute__((ext_vector_type(4)));
typedef __bf16 bf16x8 __attribute__((ext_vector_type(8)));
typedef __bf16 bf16x4 __attribute__((ext_vector_type(4)));
typedef __bf16 bf16x2 __attribute__((ext_vector_type(2)));

__device__ __forceinline__ void gload16(const void* g, void* lds) {
  auto gp = reinterpret_cast<__attribute__((address_space(1))) void*>(
      reinterpret_cast<uintptr_t>(g));
  auto lp = reinterpret_cast<__attribute__((address_space(3))) void*>(
      reinterpret_cast<uintptr_t>(lds));
  __builtin_amdgcn_global_load_lds(gp, lp, 16, 0, 0);
}

__device__ __forceinline__ f32x4 mfma16(bf16x8 a, bf16x8 b, f32x4 c) {
  return __builtin_amdgcn_mfma_f32_16x16x32_bf16(a, b, c, 0, 0, 0);
}

// ---------------- fp32 -> bf16 elementwise (hidden) ----------------
__global__ __launch_bounds__(256) void k_f32_to_bf16(const float* __restrict__ x,
                                                     __bf16* __restrict__ y) {
  const size_t e = (size_t)blockIdx.x * 256 + threadIdx.x;  // 8 elems each
  const float4* xv = (const float4*)x;
  float4 a = xv[e * 2], b = xv[e * 2 + 1];
  bf16x8 o;
  o[0] = (__bf16)a.x; o[1] = (__bf16)a.y; o[2] = (__bf16)a.z; o[3] = (__bf16)a.w;
  o[4] = (__bf16)b.x; o[5] = (__bf16)b.y; o[6] = (__bf16)b.z; o[7] = (__bf16)b.w;
  *(bf16x8*)(y + e * 8) = o;
}

// ---------------- fp32 [R][C] -> bf16 [C][R] transpose ----------------
__global__ __launch_bounds__(256) void k_transpose(const float* __restrict__ W,
                                                   __bf16* __restrict__ Wt,
                                                   int R, int C) {
  __shared__ __bf16 tb[32][33];
  const int nbx = C >> 5;
  const int c0 = (blockIdx.x % nbx) << 5;
  const int r0 = (blockIdx.x / nbx) << 5;
  const int tx = threadIdx.x & 31, ty = threadIdx.x >> 5;  // ty 0..7
#pragma unroll
  for (int i = 0; i < 32; i += 8)
    tb[ty + i][tx] = (__bf16)W[(size_t)(r0 + ty + i) * C + c0 + tx];
  __syncthreads();
#pragma unroll
  for (int i = 0; i < 32; i += 8)
    Wt[(size_t)(c0 + ty + i) * R + r0 + tx] = tb[tx][ty + i];
}

// ---------------- RoPE cos/sin tables ----------------
__global__ void k_rope_tab(const int* __restrict__ pos, float* __restrict__ cosT,
                           float* __restrict__ sinT) {
  const int t = blockIdx.x;
  const int d = threadIdx.x;  // 0..63
  const float inv = exp2f(-(float)d * (16.609640474436812f / 64.0f));  // theta^-d/64
  const float fr = (float)pos[t] * inv;
  cosT[t * 64 + d] = cosf(fr);
  sinT[t * 64 + d] = sinf(fr);
}

// ---------------- 128x128-tile bf16 GEMM (m97 structure) ----------------
// C[M][N] (fp32, +optional bias) = A[M][K] * Bt[N][K]^T
template <bool BIAS>
__global__ __launch_bounds__(256, 2) void k_gemm(const __bf16* __restrict__ A,
                                                 const __bf16* __restrict__ Bt,
                                                 const float* __restrict__ bias,
                                                 float* __restrict__ C,
                                                 int M, int N, int K) {
  __shared__ __align__(16) __bf16 As[128 * 32];
  __shared__ __align__(16) __bf16 Bs[128 * 32];
  const int tid = threadIdx.x;
  const int lane = tid & 63;
  const int w = tid >> 6;
  const int wr = w >> 1, wc = w & 1;
  const int c = lane & 15, g = lane >> 4;

  const int nbx = N >> 7;
  const int bx = blockIdx.x % nbx;
  const int by = blockIdx.x / nbx;
  const int m0 = by << 7, n0 = bx << 7;

  // staging: wave w owns tile bytes [w*2048, w*2048+2048), 2 x 1KB loads
  const int o0 = w * 2048 + lane * 16;
  const int r0 = o0 >> 6, cb0 = o0 & 63;
  const int o1 = o0 + 1024;
  const int r1 = o1 >> 6, cb1 = o1 & 63;
  const __bf16* gA0 = A + (size_t)(m0 + r0) * K + (cb0 >> 1);
  const __bf16* gA1 = A + (size_t)(m0 + r1) * K + (cb1 >> 1);
  const __bf16* gB0 = Bt + (size_t)(n0 + r0) * K + (cb0 >> 1);
  const __bf16* gB1 = Bt + (size_t)(n0 + r1) * K + (cb1 >> 1);
  char* lA0 = (char*)As + w * 2048;
  char* lA1 = lA0 + 1024;
  char* lB0 = (char*)Bs + w * 2048;
  char* lB1 = lB0 + 1024;

  f32x4 acc[4][4] = {};

  for (int kt = 0; kt < K; kt += 32) {
    __syncthreads();
    gload16(gA0 + kt, lA0);
    gload16(gA1 + kt, lA1);
    gload16(gB0 + kt, lB0);
    gload16(gB1 + kt, lB1);
    __syncthreads();
    bf16x8 af[4], bfr[4];
#pragma unroll
    for (int mi = 0; mi < 4; mi++)
      af[mi] = *(const bf16x8*)(As + ((wr * 64 + mi * 16 + c) * 32 + g * 8));
#pragma unroll
    for (int ni = 0; ni < 4; ni++)
      bfr[ni] = *(const bf16x8*)(Bs + ((wc * 64 + ni * 16 + c) * 32 + g * 8));
#pragma unroll
    for (int mi = 0; mi < 4; mi++)
#pragma unroll
      for (int ni = 0; ni < 4; ni++)
        acc[mi][ni] = mfma16(af[mi], bfr[ni], acc[mi][ni]);
  }

#pragma unroll
  for (int ni = 0; ni < 4; ni++) {
    const int col = n0 + wc * 64 + ni * 16 + c;
    const float bv = BIAS ? bias[col] : 0.0f;
#pragma unroll
    for (int mi = 0; mi < 4; mi++)
#pragma unroll
      for (int r = 0; r < 4; r++) {
        const int row = m0 + wr * 64 + mi * 16 + 4 * g + r;
        C[(size_t)row * N + col] = acc[mi][ni][r] + bv;
      }
  }
}

// ---------------- RoPE + pack: qkv fp32 -> Qp/Kp (roped bf16), Vt (transposed bf16)
__global__ __launch_bounds__(256) void k_rope_pack(
    const float* __restrict__ qkv, const float* __restrict__ cosT,
    const float* __restrict__ sinT, __bf16* __restrict__ Qp,
    __bf16* __restrict__ Kp, __bf16* __restrict__ Vt) {
  const int t0 = blockIdx.x * 64;
  const int hh = blockIdx.y;  // 0..23: 16 q heads, 4 k heads, 4 v heads
  const int tid = threadIdx.x;
  const int col0 = hh * HD;
  __shared__ __bf16 lt[64][136];
  if (hh < NH + NKV) {
    const bool isq = hh < NH;
    const float s = isq ? 0.08838834764831845f : 1.0f;  // 1/sqrt(128) folded into Q
    __bf16* base = isq ? (Qp + (size_t)hh * T_TOK * HD)
                       : (Kp + (size_t)(hh - NH) * T_TOK * HD);
#pragma unroll
    for (int jj = 0; jj < 16; jj++) {
      const int e = jj * 256 + tid;  // 64 t x 64 d2
      const int tl = e >> 6, d2 = e & 63;
      const int tt = t0 + tl;
      const float x1 = qkv[(size_t)tt * QKVO + col0 + d2];
      const float x2 = qkv[(size_t)tt * QKVO + col0 + 64 + d2];
      const float cs = cosT[tt * 64 + d2];
      const float sn = sinT[tt * 64 + d2];
      __bf16* dst = base + (size_t)tt * HD;
      dst[d2] = (__bf16)((x1 * cs - x2 * sn) * s);
      dst[64 + d2] = (__bf16)((x2 * cs + x1 * sn) * s);
    }
  } else {
    const int kv = hh - (NH + NKV);
#pragma unroll
    for (int jj = 0; jj < 32; jj++) {
      const int e = jj * 256 + tid;  // 64 t x 128 d
      const int tl = e >> 7, d = e & 127;
      lt[tl][d] = (__bf16)qkv[(size_t)(t0 + tl) * QKVO + col0 + d];
    }
    __syncthreads();
#pragma unroll
    for (int jj = 0; jj < 32; jj++) {
      const int e = jj * 256 + tid;  // 128 d x 64 t
      const int d = e >> 6, tl = e & 63;
      Vt[((size_t)kv * HD + d) * T_TOK + t0 + tl] = lt[tl][d];
    }
  }
}

// ---------------- flash attention v2: no K/V LDS, KVBLK=64, zero barriers ----
// block: (64 q rows) x (head). 4 waves, wave w owns q rows [q0+16w, +16).
// Swapped QK^T (S^T = K*Q^T): K row-major and Vt [d][t] make every MFMA
// A-fragment a contiguous 16B global load -> direct from L2, no staging.
// Only LDS: per-wave P-bounce (XOR-swizzled, 2KB/wave).
__global__ __launch_bounds__(256) void k_attn(const __bf16* __restrict__ Qp,
                                              const __bf16* __restrict__ Kp,
                                              const __bf16* __restrict__ Vt,
                                              __bf16* __restrict__ attnO) {
  __shared__ __align__(16) __bf16 Ps[4][16 * 64];  // [wave][q=16][key=64]

  const int tid = threadIdx.x;
  const int lane = tid & 63;
  const int w = tid >> 6;
  const int c = lane & 15, g = lane >> 4;
  const int h = blockIdx.y;
  const int kvh = h >> 2;  // GQA group of 4
  const int q0 = blockIdx.x * 64;
  const int i_row = q0 + w * 16 + c;  // this lane's query row

  bf16x8 qf[4];  // Q B-fragments: col=q(=c), k = 32*ds + 8*g + j
  {
    const __bf16* qbase = Qp + ((size_t)h * T_TOK + i_row) * HD;
#pragma unroll
    for (int ds = 0; ds < 4; ds++) qf[ds] = *(const bf16x8*)(qbase + ds * 32 + g * 8);
  }

  f32x4 ot[8] = {};  // O^T: ot[m][r] -> d = 16m+4g+r, q = c
  float mrun = -1e30f, lrun = 0.0f;

  const int jstart = (q0 >= WIN) ? (q0 - WIN) : 0;
  const int niter = (q0 + 64 - jstart) >> 6;

  // per-lane base pointers (advance K by 64 rows per iter; V indexed by it*64)
  const __bf16* kp = Kp + ((size_t)kvh * T_TOK + jstart + c) * HD + g * 8;
  const __bf16* vp = Vt + ((size_t)kvh * HD + c) * T_TOK + jstart + g * 8;

  char* pw = (char*)&Ps[w][0];
  const int swz = (c & 7) << 4;

  for (int it = 0; it < niter; ++it) {
    const int j0 = jstart + it * 64;

    // ---- S^T = K * Q^T : 4 key-subtiles x 4 d-steps
    f32x4 st[4] = {};
#pragma unroll
    for (int t = 0; t < 4; t++)
#pragma unroll
      for (int ds = 0; ds < 4; ds++) {
        bf16x8 kf = *(const bf16x8*)(kp + t * 16 * HD + ds * 32);
        st[t] = mfma16(kf, qf[ds], st[t]);
      }

    // ---- mask + online softmax (q = c is lane-local; keys j0+16t+4g+r)
    float p[16];
    float cmax = -1e30f;
    const int jb = i_row - j0 - 4 * g;  // i_row - j = jb - 16t - r
#pragma unroll
    for (int t = 0; t < 4; t++)
#pragma unroll
      for (int r = 0; r < 4; r++) {
        float s = st[t][r];
        // (j <= i_row) && (i_row - j <= WIN)  <=>  unsigned(i_row-j) <= WIN
        s = ((unsigned)(jb - 16 * t - r) <= WIN) ? s : -1e30f;
        p[t * 4 + r] = s;
        cmax = fmaxf(cmax, s);
      }
    cmax = fmaxf(cmax, __shfl_xor(cmax, 16));
    cmax = fmaxf(cmax, __shfl_xor(cmax, 32));

    // defer-max (T13, THR=8): skip O-rescale when max barely grows
    if (!__all(cmax <= mrun + 8.0f)) {
      const float mn = fmaxf(mrun, cmax);
      const float alpha = __expf(mrun - mn);
      lrun *= alpha;
#pragma unroll
      for (int m = 0; m < 8; m++) ot[m] *= alpha;
      mrun = mn;
    }
    float rs = 0.0f;
#pragma unroll
    for (int x = 0; x < 16; x++) {
      const float e_ = __expf(p[x] - mrun);
      p[x] = e_;
      rs += e_;
    }
    rs += __shfl_xor(rs, 16);
    rs += __shfl_xor(rs, 32);
    lrun += rs;

    // ---- P -> per-wave LDS (row=q=c, XOR-swizzled), re-read as B-fragments
#pragma unroll
    for (int t = 0; t < 4; t++) {
      bf16x4 pk;
      pk[0] = (__bf16)p[t * 4 + 0];
      pk[1] = (__bf16)p[t * 4 + 1];
      pk[2] = (__bf16)p[t * 4 + 2];
      pk[3] = (__bf16)p[t * 4 + 3];
      *(bf16x4*)(pw + c * 128 + ((t * 32 + g * 8) ^ swz)) = pk;
    }
    bf16x8 pf[2];
#pragma unroll
    for (int ks = 0; ks < 2; ks++)
      pf[ks] = *(const bf16x8*)(pw + c * 128 + ((ks * 64 + g * 16) ^ swz));

    // ---- O^T += V^T * P^T : 8 d-tiles x 2 key-subtiles, V direct from L2
#pragma unroll
    for (int m = 0; m < 8; m++) {
      const __bf16* vrow = vp + (size_t)(m * 16) * T_TOK + it * 64;
#pragma unroll
      for (int ks = 0; ks < 2; ks++) {
        bf16x8 vf = *(const bf16x8*)(vrow + ks * 32);
        ot[m] = mfma16(vf, pf[ks], ot[m]);
      }
    }

    kp += 64 * HD;
  }

  const float inv_l = 1.0f / lrun;
  __bf16* orow = attnO + (size_t)i_row * (NH * HD) + h * HD;
#pragma unroll
  for (int m = 0; m < 8; m++) {
    bf16x4 o4;
#pragma unroll
    for (int r = 0; r < 4; r++) o4[r] = (__bf16)(ot[m][r] * inv_l);
    *(bf16x4*)(orow + m * 16 + 4 * g) = o4;
  }
}

// ---------------- launcher ----------------
extern "C" void kernel_launch(void* const* d_in, const int* in_sizes, int n_in,
                              void* d_out, int out_size, void* d_ws, size_t ws_size,
                              hipStream_t stream) {
  (void)in_sizes; (void)n_in; (void)out_size; (void)ws_size;
  const float* hidden = (const float*)d_in[0];
  const int* positions = (const int*)d_in[1];
  const float* w_qkv = (const float*)d_in[2];
  const float* b_qkv = (const float*)d_in[3];
  const float* w_o = (const float*)d_in[4];
  float* out = (float*)d_out;

  char* ws = (char*)d_ws;
  __bf16* Hb = (__bf16*)ws;    ws += (size_t)T_TOK * HID * 2;        // 16 MB
  __bf16* Wqkvt = (__bf16*)ws; ws += (size_t)QKVO * HID * 2;         // 12 MB
  __bf16* Wot = (__bf16*)ws;   ws += (size_t)HID * HID * 2;          // 8 MB
  float* cosT = (float*)ws;    ws += (size_t)T_TOK * 64 * 4;         // 1 MB
  float* sinT = (float*)ws;    ws += (size_t)T_TOK * 64 * 4;         // 1 MB
  float* qkv = (float*)ws;     ws += (size_t)T_TOK * QKVO * 4;       // 48 MB
  __bf16* Qp = (__bf16*)ws;    ws += (size_t)NH * T_TOK * HD * 2;    // 16 MB
  __bf16* Kp = (__bf16*)ws;    ws += (size_t)NKV * T_TOK * HD * 2;   // 4 MB
  __bf16* Vt = (__bf16*)ws;    ws += (size_t)NKV * HD * T_TOK * 2;   // 4 MB
  __bf16* attnb = (__bf16*)ws; ws += (size_t)T_TOK * NH * HD * 2;    // 16 MB

  k_f32_to_bf16<<<T_TOK * HID / (256 * 8), 256, 0, stream>>>(hidden, Hb);
  k_transpose<<<(QKVO / 32) * (HID / 32), 256, 0, stream>>>(w_qkv, Wqkvt, HID, QKVO);
  k_transpose<<<(HID / 32) * (HID / 32), 256, 0, stream>>>(w_o, Wot, HID, HID);
  k_rope_tab<<<T_TOK, 64, 0, stream>>>(positions, cosT, sinT);
  k_gemm<true><<<(T_TOK / 128) * (QKVO / 128), 256, 0, stream>>>(
      Hb, Wqkvt, b_qkv, qkv, T_TOK, QKVO, HID);
  k_rope_pack<<<dim3(T_TOK / 64, NH + 2 * NKV), 256, 0, stream>>>(
      qkv, cosT, sinT, Qp, Kp, Vt);
  k_attn<<<dim3(T_TOK / 64, NH), 256, 0, stream>>>(Qp, Kp, Vt, attnb);
  k_gemm<false><<<(T_TOK / 128) * (HID / 128), 256, 0, stream>>>(
      attnb, Wot, nullptr, out, T_TOK, HID, HID);
}

// Round 3
// 213.913 us; speedup vs baseline: 2.0736x; 2.0736x over previous
//
#include <hip/hip_runtime.h>
#include <cstdint>

#define T_TOK 4096
#define HID 2048
#define NH 16
#define NKV 4
#define HD 128
#define WIN 1024
#define QKVO 3072

typedef float f32x4 __attribute__((ext_vector_type(4)));
typedef __bf16 bf16x8 __attribute__((ext_vector_type(8)));
typedef __bf16 bf16x4 __attribute__((ext_vector_type(4)));
typedef __bf16 bf16x2 __attribute__((ext_vector_type(2)));

__device__ __forceinline__ void gload16(const void* g, void* lds) {
  auto gp = reinterpret_cast<__attribute__((address_space(1))) void*>(
      reinterpret_cast<uintptr_t>(g));
  auto lp = reinterpret_cast<__attribute__((address_space(3))) void*>(
      reinterpret_cast<uintptr_t>(lds));
  __builtin_amdgcn_global_load_lds(gp, lp, 16, 0, 0);
}

__device__ __forceinline__ f32x4 mfma16(bf16x8 a, bf16x8 b, f32x4 c) {
  return __builtin_amdgcn_mfma_f32_16x16x32_bf16(a, b, c, 0, 0, 0);
}

// ---------------- fp32 -> bf16 elementwise (hidden) ----------------
__global__ __launch_bounds__(256) void k_f32_to_bf16(const float* __restrict__ x,
                                                     __bf16* __restrict__ y) {
  const size_t e = (size_t)blockIdx.x * 256 + threadIdx.x;  // 8 elems each
  const float4* xv = (const float4*)x;
  float4 a = xv[e * 2], b = xv[e * 2 + 1];
  bf16x8 o;
  o[0] = (__bf16)a.x; o[1] = (__bf16)a.y; o[2] = (__bf16)a.z; o[3] = (__bf16)a.w;
  o[4] = (__bf16)b.x; o[5] = (__bf16)b.y; o[6] = (__bf16)b.z; o[7] = (__bf16)b.w;
  *(bf16x8*)(y + e * 8) = o;
}

// ---------------- fp32 [R][C] -> bf16 [C][R] transpose ----------------
__global__ __launch_bounds__(256) void k_transpose(const float* __restrict__ W,
                                                   __bf16* __restrict__ Wt,
                                                   int R, int C) {
  __shared__ __bf16 tb[32][33];
  const int nbx = C >> 5;
  const int c0 = (blockIdx.x % nbx) << 5;
  const int r0 = (blockIdx.x / nbx) << 5;
  const int tx = threadIdx.x & 31, ty = threadIdx.x >> 5;  // ty 0..7
#pragma unroll
  for (int i = 0; i < 32; i += 8)
    tb[ty + i][tx] = (__bf16)W[(size_t)(r0 + ty + i) * C + c0 + tx];
  __syncthreads();
#pragma unroll
  for (int i = 0; i < 32; i += 8)
    Wt[(size_t)(c0 + ty + i) * R + r0 + tx] = tb[tx][ty + i];
}

// ---------------- RoPE cos/sin tables ----------------
__global__ void k_rope_tab(const int* __restrict__ pos, float* __restrict__ cosT,
                           float* __restrict__ sinT) {
  const int t = blockIdx.x;
  const int d = threadIdx.x;  // 0..63
  const float inv = exp2f(-(float)d * (16.609640474436812f / 64.0f));  // theta^-d/64
  const float fr = (float)pos[t] * inv;
  cosT[t * 64 + d] = cosf(fr);
  sinT[t * 64 + d] = sinf(fr);
}

// ---------------- 128x128-tile bf16 GEMM (m97 structure) ----------------
// C[M][N] (fp32, +optional bias) = A[M][K] * Bt[N][K]^T
template <bool BIAS>
__global__ __launch_bounds__(256, 2) void k_gemm(const __bf16* __restrict__ A,
                                                 const __bf16* __restrict__ Bt,
                                                 const float* __restrict__ bias,
                                                 float* __restrict__ C,
                                                 int M, int N, int K) {
  __shared__ __align__(16) __bf16 As[128 * 32];
  __shared__ __align__(16) __bf16 Bs[128 * 32];
  const int tid = threadIdx.x;
  const int lane = tid & 63;
  const int w = tid >> 6;
  const int wr = w >> 1, wc = w & 1;
  const int c = lane & 15, g = lane >> 4;

  const int nbx = N >> 7;
  const int bx = blockIdx.x % nbx;
  const int by = blockIdx.x / nbx;
  const int m0 = by << 7, n0 = bx << 7;

  // staging: wave w owns tile bytes [w*2048, w*2048+2048), 2 x 1KB loads
  const int o0 = w * 2048 + lane * 16;
  const int r0 = o0 >> 6, cb0 = o0 & 63;
  const int o1 = o0 + 1024;
  const int r1 = o1 >> 6, cb1 = o1 & 63;
  const __bf16* gA0 = A + (size_t)(m0 + r0) * K + (cb0 >> 1);
  const __bf16* gA1 = A + (size_t)(m0 + r1) * K + (cb1 >> 1);
  const __bf16* gB0 = Bt + (size_t)(n0 + r0) * K + (cb0 >> 1);
  const __bf16* gB1 = Bt + (size_t)(n0 + r1) * K + (cb1 >> 1);
  char* lA0 = (char*)As + w * 2048;
  char* lA1 = lA0 + 1024;
  char* lB0 = (char*)Bs + w * 2048;
  char* lB1 = lB0 + 1024;

  f32x4 acc[4][4] = {};

  for (int kt = 0; kt < K; kt += 32) {
    __syncthreads();
    gload16(gA0 + kt, lA0);
    gload16(gA1 + kt, lA1);
    gload16(gB0 + kt, lB0);
    gload16(gB1 + kt, lB1);
    __syncthreads();
    bf16x8 af[4], bfr[4];
#pragma unroll
    for (int mi = 0; mi < 4; mi++)
      af[mi] = *(const bf16x8*)(As + ((wr * 64 + mi * 16 + c) * 32 + g * 8));
#pragma unroll
    for (int ni = 0; ni < 4; ni++)
      bfr[ni] = *(const bf16x8*)(Bs + ((wc * 64 + ni * 16 + c) * 32 + g * 8));
#pragma unroll
    for (int mi = 0; mi < 4; mi++)
#pragma unroll
      for (int ni = 0; ni < 4; ni++)
        acc[mi][ni] = mfma16(af[mi], bfr[ni], acc[mi][ni]);
  }

#pragma unroll
  for (int ni = 0; ni < 4; ni++) {
    const int col = n0 + wc * 64 + ni * 16 + c;
    const float bv = BIAS ? bias[col] : 0.0f;
#pragma unroll
    for (int mi = 0; mi < 4; mi++)
#pragma unroll
      for (int r = 0; r < 4; r++) {
        const int row = m0 + wr * 64 + mi * 16 + 4 * g + r;
        C[(size_t)row * N + col] = acc[mi][ni][r] + bv;
      }
  }
}

// ---------------- RoPE + pack ----------------
// Q: roped, scale folded. K: roped, rows PRE-SWIZZLED (d ^= (t&7)<<3) so the
// attn kernel can global_load_lds linearly and XOR-read bank-conflict-free.
// V: transposed to [d][t] with cols pre-swizzled within each 64-tile
// (t ^= (d&7)<<3).
__global__ __launch_bounds__(256) void k_rope_pack(
    const float* __restrict__ qkv, const float* __restrict__ cosT,
    const float* __restrict__ sinT, __bf16* __restrict__ Qp,
    __bf16* __restrict__ Kp, __bf16* __restrict__ Vt) {
  const int t0 = blockIdx.x * 64;
  const int hh = blockIdx.y;  // 0..23: 16 q heads, 4 k heads, 4 v heads
  const int tid = threadIdx.x;
  const int col0 = hh * HD;
  __shared__ __bf16 lt[64][136];
  if (hh < NH + NKV) {
    const bool isq = hh < NH;
    const float s = isq ? 0.08838834764831845f : 1.0f;  // 1/sqrt(128) folded into Q
    __bf16* base = isq ? (Qp + (size_t)hh * T_TOK * HD)
                       : (Kp + (size_t)(hh - NH) * T_TOK * HD);
#pragma unroll
    for (int jj = 0; jj < 16; jj++) {
      const int e = jj * 256 + tid;  // 64 t x 64 d2
      const int tl = e >> 6, d2 = e & 63;
      const int tt = t0 + tl;
      const float x1 = qkv[(size_t)tt * QKVO + col0 + d2];
      const float x2 = qkv[(size_t)tt * QKVO + col0 + 64 + d2];
      const float cs = cosT[tt * 64 + d2];
      const float sn = sinT[tt * 64 + d2];
      __bf16* dst = base + (size_t)tt * HD;
      const int d2s = isq ? d2 : (d2 ^ ((tt & 7) << 3));  // K row swizzle
      dst[d2s] = (__bf16)((x1 * cs - x2 * sn) * s);
      dst[64 + d2s] = (__bf16)((x2 * cs + x1 * sn) * s);
    }
  } else {
    const int kv = hh - (NH + NKV);
#pragma unroll
    for (int jj = 0; jj < 32; jj++) {
      const int e = jj * 256 + tid;  // 64 t x 128 d
      const int tl = e >> 7, d = e & 127;
      lt[tl][d] = (__bf16)qkv[(size_t)(t0 + tl) * QKVO + col0 + d];
    }
    __syncthreads();
#pragma unroll
    for (int jj = 0; jj < 32; jj++) {
      const int e = jj * 256 + tid;  // 128 d x 64 t
      const int d = e >> 6, tl = e & 63;
      // col swizzle within the 64-token tile
      Vt[((size_t)kv * HD + d) * T_TOK + t0 + (tl ^ ((d & 7) << 3))] = lt[tl][d];
    }
  }
}

// ---------------- flash attention v3 ----------------
// block: (64 q rows) x (head). 4 waves, wave w owns q rows [q0+16w, +16).
// Swapped QK^T (S^T = K*Q^T) so softmax rows are lane-local (q = lane&15).
// K/V double-buffered in LDS via global_load_lds (linear dest) from
// PRE-SWIZZLED global layouts; fragment reads apply matching XOR -> bank floor.
// 2-phase pipeline: one __syncthreads per iter, prefetch issued right after.
__global__ __launch_bounds__(256, 2) void k_attn(const __bf16* __restrict__ Qp,
                                                 const __bf16* __restrict__ Kp,
                                                 const __bf16* __restrict__ Vt,
                                                 __bf16* __restrict__ attnO) {
  __shared__ __align__(16) __bf16 Ks[2][64 * 128];  // [buf][key][d] 256B rows
  __shared__ __align__(16) __bf16 Vs[2][128 * 64];  // [buf][d][key] 128B rows
  __shared__ __align__(16) __bf16 Ps[4][16 * 64];   // per-wave P bounce

  const int tid = threadIdx.x;
  const int lane = tid & 63;
  const int w = tid >> 6;
  const int c = lane & 15, g = lane >> 4;
  const int h = blockIdx.y;
  const int kvh = h >> 2;  // GQA group of 4
  const int q0 = blockIdx.x * 64;
  const int i_row = q0 + w * 16 + c;  // this lane's query row
  const int swz = (c & 7) << 4;

  bf16x8 qf[4];  // Q B-fragments: col=q(=c), k = 32*ds + 8*g + j
  {
    const __bf16* qbase = Qp + ((size_t)h * T_TOK + i_row) * HD;
#pragma unroll
    for (int ds = 0; ds < 4; ds++) qf[ds] = *(const bf16x8*)(qbase + ds * 32 + g * 8);
  }

  f32x4 ot[8] = {};  // O^T: ot[m][r] -> d = 16m+4g+r, q = c
  float mrun = -1e30f, lrun = 0.0f;

  const int jstart = (q0 >= WIN) ? (q0 - WIN) : 0;
  const int niter = (q0 + 64 - jstart) >> 6;

  // staging addresses: wave w stages K rows [16w,16w+16) and V rows [32w,32w+32)
  const char* Kg = (const char*)Kp + (size_t)kvh * T_TOK * HD * 2;
  const char* Vg = (const char*)Vt + (size_t)kvh * HD * T_TOK * 2;
  const char* kg0 = Kg + (size_t)(jstart + 16 * w + (lane >> 4)) * 256 + (lane & 15) * 16;
  const char* vg0 = Vg + (size_t)(32 * w + (lane >> 3)) * (T_TOK * 2) +
                    (size_t)jstart * 2 + (lane & 7) * 16;

  // prologue: stage tile 0 into buf 0
#pragma unroll
  for (int q = 0; q < 4; q++)
    gload16(kg0 + q * 1024, (char*)&Ks[0][0] + w * 4096 + q * 1024);
#pragma unroll
  for (int q = 0; q < 4; q++)
    gload16(vg0 + (size_t)q * 8 * (T_TOK * 2), (char*)&Vs[0][0] + w * 4096 + q * 1024);

  char* pw = (char*)&Ps[w][0];
  int cur = 0;

  for (int it = 0; it < niter; ++it) {
    const int j0 = jstart + it * 64;
    __syncthreads();  // buf[cur] staged; everyone done reading buf[cur^1]

    if (it + 1 < niter) {  // prefetch next tile into buf[cur^1]
      const char* kg = kg0 + (size_t)(it + 1) * 16384;
      const char* vg = vg0 + (size_t)(it + 1) * 128;
      char* kd = (char*)&Ks[cur ^ 1][0] + w * 4096;
      char* vd = (char*)&Vs[cur ^ 1][0] + w * 4096;
#pragma unroll
      for (int q = 0; q < 4; q++) gload16(kg + q * 1024, kd + q * 1024);
#pragma unroll
      for (int q = 0; q < 4; q++)
        gload16(vg + (size_t)q * 8 * (T_TOK * 2), vd + q * 1024);
    }

    const char* kb = (const char*)&Ks[cur][0];
    const char* vb = (const char*)&Vs[cur][0];

    // ---- S^T = K * Q^T : 4 key-subtiles x 4 d-steps
    f32x4 st[4] = {};
    __builtin_amdgcn_s_setprio(1);
#pragma unroll
    for (int t = 0; t < 4; t++)
#pragma unroll
      for (int ds = 0; ds < 4; ds++) {
        bf16x8 kf = *(const bf16x8*)(kb + (t * 16 + c) * 256 + ((ds * 64 + g * 16) ^ swz));
        st[t] = mfma16(kf, qf[ds], st[t]);
      }
    __builtin_amdgcn_s_setprio(0);

    // ---- mask + online softmax (q = c lane-local; keys j0+16t+4g+r)
    float p[16];
    float cmax = -1e30f;
    const int jb = i_row - j0 - 4 * g;  // i_row - j = jb - 16t - r
#pragma unroll
    for (int t = 0; t < 4; t++)
#pragma unroll
      for (int r = 0; r < 4; r++) {
        float s = st[t][r];
        // (j <= i_row) && (i_row - j <= WIN)  <=>  unsigned(i_row-j) <= WIN
        s = ((unsigned)(jb - 16 * t - r) <= WIN) ? s : -1e30f;
        p[t * 4 + r] = s;
        cmax = fmaxf(cmax, s);
      }
    cmax = fmaxf(cmax, __shfl_xor(cmax, 16));
    cmax = fmaxf(cmax, __shfl_xor(cmax, 32));

    // defer-max (T13, THR=8): skip O-rescale when max barely grows
    if (!__all(cmax <= mrun + 8.0f)) {
      const float mn = fmaxf(mrun, cmax);
      const float alpha = __expf(mrun - mn);
      lrun *= alpha;
#pragma unroll
      for (int m = 0; m < 8; m++) ot[m] *= alpha;
      mrun = mn;
    }
    float rs = 0.0f;
#pragma unroll
    for (int x = 0; x < 16; x++) {
      const float e_ = __expf(p[x] - mrun);
      p[x] = e_;
      rs += e_;
    }
    rs += __shfl_xor(rs, 16);
    rs += __shfl_xor(rs, 32);
    lrun += rs;

    // ---- P -> per-wave LDS (row=q=c, XOR-swizzled), re-read as B-fragments
#pragma unroll
    for (int t = 0; t < 4; t++) {
      bf16x4 pk;
      pk[0] = (__bf16)p[t * 4 + 0];
      pk[1] = (__bf16)p[t * 4 + 1];
      pk[2] = (__bf16)p[t * 4 + 2];
      pk[3] = (__bf16)p[t * 4 + 3];
      *(bf16x4*)(pw + c * 128 + ((t * 32 + g * 8) ^ swz)) = pk;
    }
    bf16x8 pf[2];
#pragma unroll
    for (int ks = 0; ks < 2; ks++)
      pf[ks] = *(const bf16x8*)(pw + c * 128 + ((ks * 64 + g * 16) ^ swz));

    // ---- O^T += V^T * P^T : 8 d-tiles x 2 key-subtiles
    __builtin_amdgcn_s_setprio(1);
#pragma unroll
    for (int m = 0; m < 8; m++)
#pragma unroll
      for (int ks = 0; ks < 2; ks++) {
        bf16x8 vf = *(const bf16x8*)(vb + (m * 16 + c) * 128 + ((ks * 64 + g * 16) ^ swz));
        ot[m] = mfma16(vf, pf[ks], ot[m]);
      }
    __builtin_amdgcn_s_setprio(0);

    cur ^= 1;
  }

  const float inv_l = 1.0f / lrun;
  __bf16* orow = attnO + (size_t)i_row * (NH * HD) + h * HD;
#pragma unroll
  for (int m = 0; m < 8; m++) {
    bf16x4 o4;
#pragma unroll
    for (int r = 0; r < 4; r++) o4[r] = (__bf16)(ot[m][r] * inv_l);
    *(bf16x4*)(orow + m * 16 + 4 * g) = o4;
  }
}

// ---------------- launcher ----------------
extern "C" void kernel_launch(void* const* d_in, const int* in_sizes, int n_in,
                              void* d_out, int out_size, void* d_ws, size_t ws_size,
                              hipStream_t stream) {
  (void)in_sizes; (void)n_in; (void)out_size; (void)ws_size;
  const float* hidden = (const float*)d_in[0];
  const int* positions = (const int*)d_in[1];
  const float* w_qkv = (const float*)d_in[2];
  const float* b_qkv = (const float*)d_in[3];
  const float* w_o = (const float*)d_in[4];
  float* out = (float*)d_out;

  char* ws = (char*)d_ws;
  __bf16* Hb = (__bf16*)ws;    ws += (size_t)T_TOK * HID * 2;        // 16 MB
  __bf16* Wqkvt = (__bf16*)ws; ws += (size_t)QKVO * HID * 2;         // 12 MB
  __bf16* Wot = (__bf16*)ws;   ws += (size_t)HID * HID * 2;          // 8 MB
  float* cosT = (float*)ws;    ws += (size_t)T_TOK * 64 * 4;         // 1 MB
  float* sinT = (float*)ws;    ws += (size_t)T_TOK * 64 * 4;         // 1 MB
  float* qkv = (float*)ws;     ws += (size_t)T_TOK * QKVO * 4;       // 48 MB
  __bf16* Qp = (__bf16*)ws;    ws += (size_t)NH * T_TOK * HD * 2;    // 16 MB
  __bf16* Kp = (__bf16*)ws;    ws += (size_t)NKV * T_TOK * HD * 2;   // 4 MB
  __bf16* Vt = (__bf16*)ws;    ws += (size_t)NKV * HD * T_TOK * 2;   // 4 MB
  __bf16* attnb = (__bf16*)ws; ws += (size_t)T_TOK * NH * HD * 2;    // 16 MB

  k_f32_to_bf16<<<T_TOK * HID / (256 * 8), 256, 0, stream>>>(hidden, Hb);
  k_transpose<<<(QKVO / 32) * (HID / 32), 256, 0, stream>>>(w_qkv, Wqkvt, HID, QKVO);
  k_transpose<<<(HID / 32) * (HID / 32), 256, 0, stream>>>(w_o, Wot, HID, HID);
  k_rope_tab<<<T_TOK, 64, 0, stream>>>(positions, cosT, sinT);
  k_gemm<true><<<(T_TOK / 128) * (QKVO / 128), 256, 0, stream>>>(
      Hb, Wqkvt, b_qkv, qkv, T_TOK, QKVO, HID);
  k_rope_pack<<<dim3(T_TOK / 64, NH + 2 * NKV), 256, 0, stream>>>(
      qkv, cosT, sinT, Qp, Kp, Vt);
  k_attn<<<dim3(T_TOK / 64, NH), 256, 0, stream>>>(Qp, Kp, Vt, attnb);
  k_gemm<false><<<(T_TOK / 128) * (HID / 128), 256, 0, stream>>>(
      attnb, Wot, nullptr, out, T_TOK, HID, HID);
}

// Round 4
// 199.434 us; speedup vs baseline: 2.2241x; 1.0726x over previous
//
#include <hip/hip_runtime.h>
#include <cstdint>

#define T_TOK 4096
#define HID 2048
#define NH 16
#define NKV 4
#define HD 128
#define WIN 1024
#define QKVO 3072

typedef float f32x4 __attribute__((ext_vector_type(4)));
typedef __bf16 bf16x8 __attribute__((ext_vector_type(8)));
typedef __bf16 bf16x4 __attribute__((ext_vector_type(4)));
typedef __bf16 bf16x2 __attribute__((ext_vector_type(2)));

__device__ __forceinline__ void gload16(const void* g, void* lds) {
  auto gp = reinterpret_cast<__attribute__((address_space(1))) void*>(
      reinterpret_cast<uintptr_t>(g));
  auto lp = reinterpret_cast<__attribute__((address_space(3))) void*>(
      reinterpret_cast<uintptr_t>(lds));
  __builtin_amdgcn_global_load_lds(gp, lp, 16, 0, 0);
}

__device__ __forceinline__ f32x4 mfma16(bf16x8 a, bf16x8 b, f32x4 c) {
  return __builtin_amdgcn_mfma_f32_16x16x32_bf16(a, b, c, 0, 0, 0);
}

// ---------------- fp32 -> bf16 elementwise (hidden) ----------------
__global__ __launch_bounds__(256) void k_f32_to_bf16(const float* __restrict__ x,
                                                     __bf16* __restrict__ y) {
  const size_t e = (size_t)blockIdx.x * 256 + threadIdx.x;  // 8 elems each
  const float4* xv = (const float4*)x;
  float4 a = xv[e * 2], b = xv[e * 2 + 1];
  bf16x8 o;
  o[0] = (__bf16)a.x; o[1] = (__bf16)a.y; o[2] = (__bf16)a.z; o[3] = (__bf16)a.w;
  o[4] = (__bf16)b.x; o[5] = (__bf16)b.y; o[6] = (__bf16)b.z; o[7] = (__bf16)b.w;
  *(bf16x8*)(y + e * 8) = o;
}

// ---------------- fp32 [R][C] -> bf16 [C][R] transpose ----------------
__global__ __launch_bounds__(256) void k_transpose(const float* __restrict__ W,
                                                   __bf16* __restrict__ Wt,
                                                   int R, int C) {
  __shared__ __bf16 tb[32][33];
  const int nbx = C >> 5;
  const int c0 = (blockIdx.x % nbx) << 5;
  const int r0 = (blockIdx.x / nbx) << 5;
  const int tx = threadIdx.x & 31, ty = threadIdx.x >> 5;  // ty 0..7
#pragma unroll
  for (int i = 0; i < 32; i += 8)
    tb[ty + i][tx] = (__bf16)W[(size_t)(r0 + ty + i) * C + c0 + tx];
  __syncthreads();
#pragma unroll
  for (int i = 0; i < 32; i += 8)
    Wt[(size_t)(c0 + ty + i) * R + r0 + tx] = tb[tx][ty + i];
}

// ---------------- RoPE cos/sin tables ----------------
__global__ void k_rope_tab(const int* __restrict__ pos, float* __restrict__ cosT,
                           float* __restrict__ sinT) {
  const int t = blockIdx.x;
  const int d = threadIdx.x;  // 0..63
  const float inv = exp2f(-(float)d * (16.609640474436812f / 64.0f));  // theta^-d/64
  const float fr = (float)pos[t] * inv;
  cosT[t * 64 + d] = cosf(fr);
  sinT[t * 64 + d] = sinf(fr);
}

// ---------------- 128x128-tile bf16 GEMM (m97 structure) ----------------
// C[M][N] (OutT, +optional fp32 bias) = A[M][K] * Bt[N][K]^T
template <bool BIAS, typename OutT>
__global__ __launch_bounds__(256, 2) void k_gemm(const __bf16* __restrict__ A,
                                                 const __bf16* __restrict__ Bt,
                                                 const float* __restrict__ bias,
                                                 OutT* __restrict__ C,
                                                 int M, int N, int K) {
  __shared__ __align__(16) __bf16 As[128 * 32];
  __shared__ __align__(16) __bf16 Bs[128 * 32];
  const int tid = threadIdx.x;
  const int lane = tid & 63;
  const int w = tid >> 6;
  const int wr = w >> 1, wc = w & 1;
  const int c = lane & 15, g = lane >> 4;

  const int nbx = N >> 7;
  const int bx = blockIdx.x % nbx;
  const int by = blockIdx.x / nbx;
  const int m0 = by << 7, n0 = bx << 7;

  // staging: wave w owns tile bytes [w*2048, w*2048+2048), 2 x 1KB loads
  const int o0 = w * 2048 + lane * 16;
  const int r0 = o0 >> 6, cb0 = o0 & 63;
  const int o1 = o0 + 1024;
  const int r1 = o1 >> 6, cb1 = o1 & 63;
  const __bf16* gA0 = A + (size_t)(m0 + r0) * K + (cb0 >> 1);
  const __bf16* gA1 = A + (size_t)(m0 + r1) * K + (cb1 >> 1);
  const __bf16* gB0 = Bt + (size_t)(n0 + r0) * K + (cb0 >> 1);
  const __bf16* gB1 = Bt + (size_t)(n0 + r1) * K + (cb1 >> 1);
  char* lA0 = (char*)As + w * 2048;
  char* lA1 = lA0 + 1024;
  char* lB0 = (char*)Bs + w * 2048;
  char* lB1 = lB0 + 1024;

  f32x4 acc[4][4] = {};

  for (int kt = 0; kt < K; kt += 32) {
    __syncthreads();
    gload16(gA0 + kt, lA0);
    gload16(gA1 + kt, lA1);
    gload16(gB0 + kt, lB0);
    gload16(gB1 + kt, lB1);
    __syncthreads();
    bf16x8 af[4], bfr[4];
#pragma unroll
    for (int mi = 0; mi < 4; mi++)
      af[mi] = *(const bf16x8*)(As + ((wr * 64 + mi * 16 + c) * 32 + g * 8));
#pragma unroll
    for (int ni = 0; ni < 4; ni++)
      bfr[ni] = *(const bf16x8*)(Bs + ((wc * 64 + ni * 16 + c) * 32 + g * 8));
#pragma unroll
    for (int mi = 0; mi < 4; mi++)
#pragma unroll
      for (int ni = 0; ni < 4; ni++)
        acc[mi][ni] = mfma16(af[mi], bfr[ni], acc[mi][ni]);
  }

#pragma unroll
  for (int ni = 0; ni < 4; ni++) {
    const int col = n0 + wc * 64 + ni * 16 + c;
    const float bv = BIAS ? bias[col] : 0.0f;
#pragma unroll
    for (int mi = 0; mi < 4; mi++)
#pragma unroll
      for (int r = 0; r < 4; r++) {
        const int row = m0 + wr * 64 + mi * 16 + 4 * g + r;
        C[(size_t)row * N + col] = (OutT)(acc[mi][ni][r] + bv);
      }
  }
}

// ---------------- RoPE + pack (bf16 qkv input) ----------------
// Q: roped, scale folded. K: roped, rows PRE-SWIZZLED (d ^= (t&7)<<3).
// V: transposed to [d][t], cols pre-swizzled per 64-tile (t ^= (d&7)<<3).
__global__ __launch_bounds__(256) void k_rope_pack(
    const __bf16* __restrict__ qkv, const float* __restrict__ cosT,
    const float* __restrict__ sinT, __bf16* __restrict__ Qp,
    __bf16* __restrict__ Kp, __bf16* __restrict__ Vt) {
  const int t0 = blockIdx.x * 64;
  const int hh = blockIdx.y;  // 0..23: 16 q heads, 4 k heads, 4 v heads
  const int tid = threadIdx.x;
  const int col0 = hh * HD;
  __shared__ __bf16 lt[64][136];
  if (hh < NH + NKV) {
    const bool isq = hh < NH;
    const float s = isq ? 0.08838834764831845f : 1.0f;  // 1/sqrt(128) folded into Q
    __bf16* base = isq ? (Qp + (size_t)hh * T_TOK * HD)
                       : (Kp + (size_t)(hh - NH) * T_TOK * HD);
#pragma unroll
    for (int jj = 0; jj < 2; jj++) {
      const int e = jj * 256 + tid;  // 64 t x 8 chunks of 8
      const int tl = e >> 3, ch = e & 7;
      const int tt = t0 + tl;
      const bf16x8 x1 = *(const bf16x8*)(qkv + (size_t)tt * QKVO + col0 + ch * 8);
      const bf16x8 x2 = *(const bf16x8*)(qkv + (size_t)tt * QKVO + col0 + 64 + ch * 8);
      const float4 c0 = *(const float4*)(cosT + tt * 64 + ch * 8);
      const float4 c1 = *(const float4*)(cosT + tt * 64 + ch * 8 + 4);
      const float4 s0 = *(const float4*)(sinT + tt * 64 + ch * 8);
      const float4 s1 = *(const float4*)(sinT + tt * 64 + ch * 8 + 4);
      const float cs[8] = {c0.x, c0.y, c0.z, c0.w, c1.x, c1.y, c1.z, c1.w};
      const float sn[8] = {s0.x, s0.y, s0.z, s0.w, s1.x, s1.y, s1.z, s1.w};
      bf16x8 o1, o2;
#pragma unroll
      for (int i = 0; i < 8; i++) {
        const float a = (float)x1[i], b = (float)x2[i];
        o1[i] = (__bf16)((a * cs[i] - b * sn[i]) * s);
        o2[i] = (__bf16)((b * cs[i] + a * sn[i]) * s);
      }
      const int d2s = isq ? ch * 8 : ((ch * 8) ^ ((tt & 7) << 3));
      __bf16* dst = base + (size_t)tt * HD;
      *(bf16x8*)(dst + d2s) = o1;
      *(bf16x8*)(dst + 64 + d2s) = o2;
    }
  } else {
    const int kv = hh - (NH + NKV);
#pragma unroll
    for (int jj = 0; jj < 4; jj++) {
      const int e = jj * 256 + tid;  // 64 t x 16 chunks of 8
      const int tl = e >> 4, dc = e & 15;
      *(bf16x8*)&lt[tl][dc * 8] =
          *(const bf16x8*)(qkv + (size_t)(t0 + tl) * QKVO + col0 + dc * 8);
    }
    __syncthreads();
#pragma unroll
    for (int jj = 0; jj < 32; jj++) {
      const int e = jj * 256 + tid;  // 128 d x 64 t
      const int d = e >> 6, tl = e & 63;
      Vt[((size_t)kv * HD + d) * T_TOK + t0 + (tl ^ ((d & 7) << 3))] = lt[tl][d];
    }
  }
}

// ---------------- flash attention v4: QBLK=128, 8 waves ----------------
// block: (128 q rows) x (head). 8 waves, wave w owns q rows [q0+16w, +16).
// Swapped QK^T (S^T = K*Q^T) so softmax rows are lane-local (q = lane&15).
// K/V double-buffered in LDS via global_load_lds from PRE-SWIZZLED global
// layouts; fragment reads apply matching XOR. One __syncthreads per iter.
// mrun init 0 (max-floor): safe for fully-masked first tiles of high waves.
__global__ __launch_bounds__(512, 4) void k_attn(const __bf16* __restrict__ Qp,
                                                 const __bf16* __restrict__ Kp,
                                                 const __bf16* __restrict__ Vt,
                                                 __bf16* __restrict__ attnO) {
  __shared__ __align__(16) __bf16 Ks[2][64 * 128];  // [buf][key][d] 256B rows, 2x16KB
  __shared__ __align__(16) __bf16 Vs[2][128 * 64];  // [buf][d][key] 128B rows, 2x16KB
  __shared__ __align__(16) __bf16 Ps[8][16 * 64];   // per-wave P bounce, 16KB

  const int tid = threadIdx.x;
  const int lane = tid & 63;
  const int w = tid >> 6;  // 0..7
  const int c = lane & 15, g = lane >> 4;
  const int h = blockIdx.y;
  const int kvh = h >> 2;  // GQA group of 4
  const int qb = (int)(gridDim.x - 1) - (int)blockIdx.x;  // heavy blocks first
  const int q0 = qb * 128;
  const int i_row = q0 + w * 16 + c;  // this lane's query row
  const int swz = (c & 7) << 4;

  bf16x8 qf[4];  // Q B-fragments: col=q(=c), k = 32*ds + 8*g + j
  {
    const __bf16* qbase = Qp + ((size_t)h * T_TOK + i_row) * HD;
#pragma unroll
    for (int ds = 0; ds < 4; ds++) qf[ds] = *(const bf16x8*)(qbase + ds * 32 + g * 8);
  }

  f32x4 ot[8] = {};  // O^T: ot[m][r] -> d = 16m+4g+r, q = c
  float mrun = 0.0f, lrun = 0.0f;  // mrun=0 max-floor (see header comment)

  const int jstart = (q0 >= WIN) ? (q0 - WIN) : 0;
  const int niter = (q0 + 128 - jstart) >> 6;

  // staging: wave w stages K rows [8w,8w+8) and V rows [16w,16w+16)
  const char* Kg = (const char*)Kp + (size_t)kvh * T_TOK * HD * 2;
  const char* Vg = (const char*)Vt + (size_t)kvh * HD * T_TOK * 2;
  const char* kg0 = Kg + (size_t)(jstart + 8 * w + (lane >> 4)) * 256 + (lane & 15) * 16;
  const char* vg0 = Vg + (size_t)(16 * w + (lane >> 3)) * (T_TOK * 2) +
                    (size_t)jstart * 2 + (lane & 7) * 16;

  // prologue: stage tile 0 into buf 0 (wave w -> bytes [w*2048, +2048))
#pragma unroll
  for (int q = 0; q < 2; q++)
    gload16(kg0 + q * 1024, (char*)&Ks[0][0] + w * 2048 + q * 1024);
#pragma unroll
  for (int q = 0; q < 2; q++)
    gload16(vg0 + (size_t)q * 8 * (T_TOK * 2), (char*)&Vs[0][0] + w * 2048 + q * 1024);

  char* pw = (char*)&Ps[w][0];
  int cur = 0;

  for (int it = 0; it < niter; ++it) {
    const int j0 = jstart + it * 64;
    __syncthreads();  // buf[cur] staged; everyone done reading buf[cur^1]

    if (it + 1 < niter) {  // prefetch next tile into buf[cur^1]
      const char* kg = kg0 + (size_t)(it + 1) * 16384;
      const char* vg = vg0 + (size_t)(it + 1) * 128;
      char* kd = (char*)&Ks[cur ^ 1][0] + w * 2048;
      char* vd = (char*)&Vs[cur ^ 1][0] + w * 2048;
#pragma unroll
      for (int q = 0; q < 2; q++) gload16(kg + q * 1024, kd + q * 1024);
#pragma unroll
      for (int q = 0; q < 2; q++)
        gload16(vg + (size_t)q * 8 * (T_TOK * 2), vd + q * 1024);
    }

    const char* kb = (const char*)&Ks[cur][0];
    const char* vb = (const char*)&Vs[cur][0];

    // ---- S^T = K * Q^T : 4 key-subtiles x 4 d-steps
    f32x4 st[4] = {};
    __builtin_amdgcn_s_setprio(1);
#pragma unroll
    for (int t = 0; t < 4; t++)
#pragma unroll
      for (int ds = 0; ds < 4; ds++) {
        bf16x8 kf = *(const bf16x8*)(kb + (t * 16 + c) * 256 + ((ds * 64 + g * 16) ^ swz));
        st[t] = mfma16(kf, qf[ds], st[t]);
      }
    __builtin_amdgcn_s_setprio(0);

    // ---- mask + online softmax (q = c lane-local; keys j0+16t+4g+r)
    float p[16];
    float cmax = -1e30f;
    const int jb = i_row - j0 - 4 * g;  // i_row - j = jb - 16t - r
#pragma unroll
    for (int t = 0; t < 4; t++)
#pragma unroll
      for (int r = 0; r < 4; r++) {
        float s = st[t][r];
        // (j <= i_row) && (i_row - j <= WIN)  <=>  unsigned(i_row-j) <= WIN
        s = ((unsigned)(jb - 16 * t - r) <= WIN) ? s : -1e30f;
        p[t * 4 + r] = s;
        cmax = fmaxf(cmax, s);
      }
    cmax = fmaxf(cmax, __shfl_xor(cmax, 16));
    cmax = fmaxf(cmax, __shfl_xor(cmax, 32));

    // defer-max (T13, THR=8): skip O-rescale when max barely grows
    if (!__all(cmax <= mrun + 8.0f)) {
      const float mn = fmaxf(mrun, cmax);
      const float alpha = __expf(mrun - mn);
      lrun *= alpha;
#pragma unroll
      for (int m = 0; m < 8; m++) ot[m] *= alpha;
      mrun = mn;
    }
    float rs = 0.0f;
#pragma unroll
    for (int x = 0; x < 16; x++) {
      const float e_ = __expf(p[x] - mrun);
      p[x] = e_;
      rs += e_;
    }
    rs += __shfl_xor(rs, 16);
    rs += __shfl_xor(rs, 32);
    lrun += rs;

    // ---- P -> per-wave LDS (row=q=c, XOR-swizzled), re-read as B-fragments
#pragma unroll
    for (int t = 0; t < 4; t++) {
      bf16x4 pk;
      pk[0] = (__bf16)p[t * 4 + 0];
      pk[1] = (__bf16)p[t * 4 + 1];
      pk[2] = (__bf16)p[t * 4 + 2];
      pk[3] = (__bf16)p[t * 4 + 3];
      *(bf16x4*)(pw + c * 128 + ((t * 32 + g * 8) ^ swz)) = pk;
    }
    bf16x8 pf[2];
#pragma unroll
    for (int ks = 0; ks < 2; ks++)
      pf[ks] = *(const bf16x8*)(pw + c * 128 + ((ks * 64 + g * 16) ^ swz));

    // ---- O^T += V^T * P^T : 8 d-tiles x 2 key-subtiles
    __builtin_amdgcn_s_setprio(1);
#pragma unroll
    for (int m = 0; m < 8; m++)
#pragma unroll
      for (int ks = 0; ks < 2; ks++) {
        bf16x8 vf = *(const bf16x8*)(vb + (m * 16 + c) * 128 + ((ks * 64 + g * 16) ^ swz));
        ot[m] = mfma16(vf, pf[ks], ot[m]);
      }
    __builtin_amdgcn_s_setprio(0);

    cur ^= 1;
  }

  const float inv_l = 1.0f / lrun;
  __bf16* orow = attnO + (size_t)i_row * (NH * HD) + h * HD;
#pragma unroll
  for (int m = 0; m < 8; m++) {
    bf16x4 o4;
#pragma unroll
    for (int r = 0; r < 4; r++) o4[r] = (__bf16)(ot[m][r] * inv_l);
    *(bf16x4*)(orow + m * 16 + 4 * g) = o4;
  }
}

// ---------------- launcher ----------------
extern "C" void kernel_launch(void* const* d_in, const int* in_sizes, int n_in,
                              void* d_out, int out_size, void* d_ws, size_t ws_size,
                              hipStream_t stream) {
  (void)in_sizes; (void)n_in; (void)out_size; (void)ws_size;
  const float* hidden = (const float*)d_in[0];
  const int* positions = (const int*)d_in[1];
  const float* w_qkv = (const float*)d_in[2];
  const float* b_qkv = (const float*)d_in[3];
  const float* w_o = (const float*)d_in[4];
  float* out = (float*)d_out;

  char* ws = (char*)d_ws;
  __bf16* Hb = (__bf16*)ws;    ws += (size_t)T_TOK * HID * 2;        // 16 MB
  __bf16* Wqkvt = (__bf16*)ws; ws += (size_t)QKVO * HID * 2;         // 12 MB
  __bf16* Wot = (__bf16*)ws;   ws += (size_t)HID * HID * 2;          // 8 MB
  float* cosT = (float*)ws;    ws += (size_t)T_TOK * 64 * 4;         // 1 MB
  float* sinT = (float*)ws;    ws += (size_t)T_TOK * 64 * 4;         // 1 MB
  __bf16* qkv = (__bf16*)ws;   ws += (size_t)T_TOK * QKVO * 2;       // 24 MB
  __bf16* Qp = (__bf16*)ws;    ws += (size_t)NH * T_TOK * HD * 2;    // 16 MB
  __bf16* Kp = (__bf16*)ws;    ws += (size_t)NKV * T_TOK * HD * 2;   // 4 MB
  __bf16* Vt = (__bf16*)ws;    ws += (size_t)NKV * HD * T_TOK * 2;   // 4 MB
  __bf16* attnb = (__bf16*)ws; ws += (size_t)T_TOK * NH * HD * 2;    // 16 MB

  k_f32_to_bf16<<<T_TOK * HID / (256 * 8), 256, 0, stream>>>(hidden, Hb);
  k_transpose<<<(QKVO / 32) * (HID / 32), 256, 0, stream>>>(w_qkv, Wqkvt, HID, QKVO);
  k_transpose<<<(HID / 32) * (HID / 32), 256, 0, stream>>>(w_o, Wot, HID, HID);
  k_rope_tab<<<T_TOK, 64, 0, stream>>>(positions, cosT, sinT);
  k_gemm<true, __bf16><<<(T_TOK / 128) * (QKVO / 128), 256, 0, stream>>>(
      Hb, Wqkvt, b_qkv, qkv, T_TOK, QKVO, HID);
  k_rope_pack<<<dim3(T_TOK / 64, NH + 2 * NKV), 256, 0, stream>>>(
      qkv, cosT, sinT, Qp, Kp, Vt);
  k_attn<<<dim3(T_TOK / 128, NH), 512, 0, stream>>>(Qp, Kp, Vt, attnb);
  k_gemm<false, float><<<(T_TOK / 128) * (HID / 128), 256, 0, stream>>>(
      attnb, Wot, nullptr, out, T_TOK, HID, HID);
}

// Round 5
// 190.892 us; speedup vs baseline: 2.3237x; 1.0447x over previous
//
#include <hip/hip_runtime.h>
#include <cstdint>

#define T_TOK 4096
#define HID 2048
#define NH 16
#define NKV 4
#define HD 128
#define WIN 1024
#define QKVO 3072

typedef float f32x4 __attribute__((ext_vector_type(4)));
typedef __bf16 bf16x8 __attribute__((ext_vector_type(8)));
typedef __bf16 bf16x4 __attribute__((ext_vector_type(4)));
typedef __bf16 bf16x2 __attribute__((ext_vector_type(2)));

__device__ __forceinline__ void gload16(const void* g, void* lds) {
  auto gp = reinterpret_cast<__attribute__((address_space(1))) void*>(
      reinterpret_cast<uintptr_t>(g));
  auto lp = reinterpret_cast<__attribute__((address_space(3))) void*>(
      reinterpret_cast<uintptr_t>(lds));
  __builtin_amdgcn_global_load_lds(gp, lp, 16, 0, 0);
}

__device__ __forceinline__ f32x4 mfma16(bf16x8 a, bf16x8 b, f32x4 c) {
  return __builtin_amdgcn_mfma_f32_16x16x32_bf16(a, b, c, 0, 0, 0);
}

// ---------------- fp32 -> bf16 elementwise (hidden) ----------------
__global__ __launch_bounds__(256) void k_f32_to_bf16(const float* __restrict__ x,
                                                     __bf16* __restrict__ y) {
  const size_t e = (size_t)blockIdx.x * 256 + threadIdx.x;  // 8 elems each
  const float4* xv = (const float4*)x;
  float4 a = xv[e * 2], b = xv[e * 2 + 1];
  bf16x8 o;
  o[0] = (__bf16)a.x; o[1] = (__bf16)a.y; o[2] = (__bf16)a.z; o[3] = (__bf16)a.w;
  o[4] = (__bf16)b.x; o[5] = (__bf16)b.y; o[6] = (__bf16)b.z; o[7] = (__bf16)b.w;
  *(bf16x8*)(y + e * 8) = o;
}

// ---------------- fp32 [R][C] -> bf16 [C][R] transpose ----------------
__global__ __launch_bounds__(256) void k_transpose(const float* __restrict__ W,
                                                   __bf16* __restrict__ Wt,
                                                   int R, int C) {
  __shared__ __bf16 tb[32][33];
  const int nbx = C >> 5;
  const int c0 = (blockIdx.x % nbx) << 5;
  const int r0 = (blockIdx.x / nbx) << 5;
  const int tx = threadIdx.x & 31, ty = threadIdx.x >> 5;  // ty 0..7
#pragma unroll
  for (int i = 0; i < 32; i += 8)
    tb[ty + i][tx] = (__bf16)W[(size_t)(r0 + ty + i) * C + c0 + tx];
  __syncthreads();
#pragma unroll
  for (int i = 0; i < 32; i += 8)
    Wt[(size_t)(c0 + ty + i) * R + r0 + tx] = tb[tx][ty + i];
}

// ---------------- RoPE cos/sin tables ----------------
__global__ void k_rope_tab(const int* __restrict__ pos, float* __restrict__ cosT,
                           float* __restrict__ sinT) {
  const int t = blockIdx.x;
  const int d = threadIdx.x;  // 0..63
  const float inv = exp2f(-(float)d * (16.609640474436812f / 64.0f));  // theta^-d/64
  const float fr = (float)pos[t] * inv;
  cosT[t * 64 + d] = cosf(fr);
  sinT[t * 64 + d] = sinf(fr);
}

// ---------------- 128x128-tile bf16 GEMM, v2 ----------------
// C[M][N] (OutT, +optional fp32 bias) = A[M][K] * Bt[N][K]^T
// vs v1 (m97 2-barrier): (1) double-buffered LDS, stage-before-compute, one
// barrier/iter (compiler's vmcnt(0)@barrier guarantees staged data visible);
// (2) dual-side granule swizzle slot = g ^ ((row>>1)&3): read conflicts
// 8-way -> 2-way(free); (3) XCD supertile remap: each XCD owns one 512-row
// st-row (A-panel 2MB L2-resident), 4x4-block supertiles (B-chunk 2MB in L2).
// Requires M == 4096 (8 st-rows) and grid % 128 == 0 (both call sites hold).
template <bool BIAS, typename OutT>
__global__ __launch_bounds__(256, 2) void k_gemm(const __bf16* __restrict__ A,
                                                 const __bf16* __restrict__ Bt,
                                                 const float* __restrict__ bias,
                                                 OutT* __restrict__ C,
                                                 int M, int N, int K) {
  __shared__ __align__(16) __bf16 As[2][128 * 32];
  __shared__ __align__(16) __bf16 Bs[2][128 * 32];
  const int tid = threadIdx.x;
  const int lane = tid & 63;
  const int w = tid >> 6;
  const int wr = w >> 1, wc = w & 1;
  const int c = lane & 15, g = lane >> 4;
  const int gsw = g ^ ((c >> 1) & 3);  // read-side granule swizzle (same all mi/ni)

  // XCD supertile remap (bijective: grid = 8 XCDs * spx supertiles * 16 blocks)
  const int nstc = N >> 9;                 // supertile cols (512 elems each)
  const int bid = blockIdx.x;
  const int xcd = bid & 7;
  const int j = bid >> 3;
  const int spx = (int)(gridDim.x >> 7);   // supertiles per XCD
  const int s = xcd * spx + (j >> 4);
  const int q = j & 15;
  const int by = (s / nstc) * 4 + (q >> 2);
  const int bx = (s % nstc) * 4 + (q & 3);
  const int m0 = by << 7, n0 = bx << 7;

  // staging: wave w owns tile bytes [w*2048, +2048), 2 x 1KB loads.
  // LDS dest linear; SOURCE k-chunk pre-swizzled so granule (r, slot) holds
  // source chunk slot ^ ((r>>1)&3).
  const int o0 = w * 2048 + lane * 16;
  const int r0 = o0 >> 6;
  const int g0 = (lane & 3) ^ ((r0 >> 1) & 3);
  const int o1 = o0 + 1024;
  const int r1 = o1 >> 6;
  const int g1 = (lane & 3) ^ ((r1 >> 1) & 3);
  const __bf16* gA0 = A + (size_t)(m0 + r0) * K + g0 * 8;
  const __bf16* gA1 = A + (size_t)(m0 + r1) * K + g1 * 8;
  const __bf16* gB0 = Bt + (size_t)(n0 + r0) * K + g0 * 8;
  const __bf16* gB1 = Bt + (size_t)(n0 + r1) * K + g1 * 8;

  f32x4 acc[4][4] = {};

  // prologue: stage tile 0 into buf 0
  {
    char* la = (char*)&As[0][0];
    char* lb = (char*)&Bs[0][0];
    gload16(gA0, la + o0);
    gload16(gA1, la + o1);
    gload16(gB0, lb + o0);
    gload16(gB1, lb + o1);
  }
  __syncthreads();

  int cur = 0;
  for (int kt = 0; kt < K; kt += 32) {
    if (kt + 32 < K) {  // stage next tile into buf cur^1 (overlaps compute)
      char* la = (char*)&As[0][0] + (cur ^ 1) * 8192;
      char* lb = (char*)&Bs[0][0] + (cur ^ 1) * 8192;
      gload16(gA0 + kt + 32, la + o0);
      gload16(gA1 + kt + 32, la + o1);
      gload16(gB0 + kt + 32, lb + o0);
      gload16(gB1 + kt + 32, lb + o1);
    }
    const __bf16* as = &As[0][0] + cur * 4096;
    const __bf16* bs = &Bs[0][0] + cur * 4096;
    bf16x8 af[4], bfr[4];
#pragma unroll
    for (int mi = 0; mi < 4; mi++)
      af[mi] = *(const bf16x8*)(as + (wr * 64 + mi * 16 + c) * 32 + gsw * 8);
#pragma unroll
    for (int ni = 0; ni < 4; ni++)
      bfr[ni] = *(const bf16x8*)(bs + (wc * 64 + ni * 16 + c) * 32 + gsw * 8);
#pragma unroll
    for (int mi = 0; mi < 4; mi++)
#pragma unroll
      for (int ni = 0; ni < 4; ni++)
        acc[mi][ni] = mfma16(af[mi], bfr[ni], acc[mi][ni]);
    __syncthreads();  // drains this iter's staging loads + publishes buf cur^1
    cur ^= 1;
  }

#pragma unroll
  for (int ni = 0; ni < 4; ni++) {
    const int col = n0 + wc * 64 + ni * 16 + c;
    const float bv = BIAS ? bias[col] : 0.0f;
#pragma unroll
    for (int mi = 0; mi < 4; mi++)
#pragma unroll
      for (int r = 0; r < 4; r++) {
        const int row = m0 + wr * 64 + mi * 16 + 4 * g + r;
        C[(size_t)row * N + col] = (OutT)(acc[mi][ni][r] + bv);
      }
  }
}

// ---------------- RoPE + pack (bf16 qkv input) ----------------
// Q: roped, scale folded. K: roped, rows PRE-SWIZZLED (d ^= (t&7)<<3).
// V: transposed to [d][t], cols pre-swizzled per 64-tile (t ^= (d&7)<<3).
__global__ __launch_bounds__(256) void k_rope_pack(
    const __bf16* __restrict__ qkv, const float* __restrict__ cosT,
    const float* __restrict__ sinT, __bf16* __restrict__ Qp,
    __bf16* __restrict__ Kp, __bf16* __restrict__ Vt) {
  const int t0 = blockIdx.x * 64;
  const int hh = blockIdx.y;  // 0..23: 16 q heads, 4 k heads, 4 v heads
  const int tid = threadIdx.x;
  const int col0 = hh * HD;
  __shared__ __bf16 lt[64][136];
  if (hh < NH + NKV) {
    const bool isq = hh < NH;
    const float s = isq ? 0.08838834764831845f : 1.0f;  // 1/sqrt(128) folded into Q
    __bf16* base = isq ? (Qp + (size_t)hh * T_TOK * HD)
                       : (Kp + (size_t)(hh - NH) * T_TOK * HD);
#pragma unroll
    for (int jj = 0; jj < 2; jj++) {
      const int e = jj * 256 + tid;  // 64 t x 8 chunks of 8
      const int tl = e >> 3, ch = e & 7;
      const int tt = t0 + tl;
      const bf16x8 x1 = *(const bf16x8*)(qkv + (size_t)tt * QKVO + col0 + ch * 8);
      const bf16x8 x2 = *(const bf16x8*)(qkv + (size_t)tt * QKVO + col0 + 64 + ch * 8);
      const float4 c0 = *(const float4*)(cosT + tt * 64 + ch * 8);
      const float4 c1 = *(const float4*)(cosT + tt * 64 + ch * 8 + 4);
      const float4 s0 = *(const float4*)(sinT + tt * 64 + ch * 8);
      const float4 s1 = *(const float4*)(sinT + tt * 64 + ch * 8 + 4);
      const float cs[8] = {c0.x, c0.y, c0.z, c0.w, c1.x, c1.y, c1.z, c1.w};
      const float sn[8] = {s0.x, s0.y, s0.z, s0.w, s1.x, s1.y, s1.z, s1.w};
      bf16x8 o1, o2;
#pragma unroll
      for (int i = 0; i < 8; i++) {
        const float a = (float)x1[i], b = (float)x2[i];
        o1[i] = (__bf16)((a * cs[i] - b * sn[i]) * s);
        o2[i] = (__bf16)((b * cs[i] + a * sn[i]) * s);
      }
      const int d2s = isq ? ch * 8 : ((ch * 8) ^ ((tt & 7) << 3));
      __bf16* dst = base + (size_t)tt * HD;
      *(bf16x8*)(dst + d2s) = o1;
      *(bf16x8*)(dst + 64 + d2s) = o2;
    }
  } else {
    const int kv = hh - (NH + NKV);
#pragma unroll
    for (int jj = 0; jj < 4; jj++) {
      const int e = jj * 256 + tid;  // 64 t x 16 chunks of 8
      const int tl = e >> 4, dc = e & 15;
      *(bf16x8*)&lt[tl][dc * 8] =
          *(const bf16x8*)(qkv + (size_t)(t0 + tl) * QKVO + col0 + dc * 8);
    }
    __syncthreads();
#pragma unroll
    for (int jj = 0; jj < 32; jj++) {
      const int e = jj * 256 + tid;  // 128 d x 64 t
      const int d = e >> 6, tl = e & 63;
      Vt[((size_t)kv * HD + d) * T_TOK + t0 + (tl ^ ((d & 7) << 3))] = lt[tl][d];
    }
  }
}

// ---------------- flash attention v4: QBLK=128, 8 waves ----------------
// block: (128 q rows) x (head). 8 waves, wave w owns q rows [q0+16w, +16).
// Swapped QK^T (S^T = K*Q^T) so softmax rows are lane-local (q = lane&15).
// K/V double-buffered in LDS via global_load_lds from PRE-SWIZZLED global
// layouts; fragment reads apply matching XOR. One __syncthreads per iter.
// mrun init 0 (max-floor): safe for fully-masked first tiles of high waves.
__global__ __launch_bounds__(512, 4) void k_attn(const __bf16* __restrict__ Qp,
                                                 const __bf16* __restrict__ Kp,
                                                 const __bf16* __restrict__ Vt,
                                                 __bf16* __restrict__ attnO) {
  __shared__ __align__(16) __bf16 Ks[2][64 * 128];  // [buf][key][d] 256B rows, 2x16KB
  __shared__ __align__(16) __bf16 Vs[2][128 * 64];  // [buf][d][key] 128B rows, 2x16KB
  __shared__ __align__(16) __bf16 Ps[8][16 * 64];   // per-wave P bounce, 16KB

  const int tid = threadIdx.x;
  const int lane = tid & 63;
  const int w = tid >> 6;  // 0..7
  const int c = lane & 15, g = lane >> 4;
  const int h = blockIdx.y;
  const int kvh = h >> 2;  // GQA group of 4
  const int qb = (int)(gridDim.x - 1) - (int)blockIdx.x;  // heavy blocks first
  const int q0 = qb * 128;
  const int i_row = q0 + w * 16 + c;  // this lane's query row
  const int swz = (c & 7) << 4;

  bf16x8 qf[4];  // Q B-fragments: col=q(=c), k = 32*ds + 8*g + j
  {
    const __bf16* qbase = Qp + ((size_t)h * T_TOK + i_row) * HD;
#pragma unroll
    for (int ds = 0; ds < 4; ds++) qf[ds] = *(const bf16x8*)(qbase + ds * 32 + g * 8);
  }

  f32x4 ot[8] = {};  // O^T: ot[m][r] -> d = 16m+4g+r, q = c
  float mrun = 0.0f, lrun = 0.0f;  // mrun=0 max-floor (see header comment)

  const int jstart = (q0 >= WIN) ? (q0 - WIN) : 0;
  const int niter = (q0 + 128 - jstart) >> 6;

  // staging: wave w stages K rows [8w,8w+8) and V rows [16w,16w+16)
  const char* Kg = (const char*)Kp + (size_t)kvh * T_TOK * HD * 2;
  const char* Vg = (const char*)Vt + (size_t)kvh * HD * T_TOK * 2;
  const char* kg0 = Kg + (size_t)(jstart + 8 * w + (lane >> 4)) * 256 + (lane & 15) * 16;
  const char* vg0 = Vg + (size_t)(16 * w + (lane >> 3)) * (T_TOK * 2) +
                    (size_t)jstart * 2 + (lane & 7) * 16;

  // prologue: stage tile 0 into buf 0 (wave w -> bytes [w*2048, +2048))
#pragma unroll
  for (int q = 0; q < 2; q++)
    gload16(kg0 + q * 1024, (char*)&Ks[0][0] + w * 2048 + q * 1024);
#pragma unroll
  for (int q = 0; q < 2; q++)
    gload16(vg0 + (size_t)q * 8 * (T_TOK * 2), (char*)&Vs[0][0] + w * 2048 + q * 1024);

  char* pw = (char*)&Ps[w][0];
  int cur = 0;

  for (int it = 0; it < niter; ++it) {
    const int j0 = jstart + it * 64;
    __syncthreads();  // buf[cur] staged; everyone done reading buf[cur^1]

    if (it + 1 < niter) {  // prefetch next tile into buf[cur^1]
      const char* kg = kg0 + (size_t)(it + 1) * 16384;
      const char* vg = vg0 + (size_t)(it + 1) * 128;
      char* kd = (char*)&Ks[cur ^ 1][0] + w * 2048;
      char* vd = (char*)&Vs[cur ^ 1][0] + w * 2048;
#pragma unroll
      for (int q = 0; q < 2; q++) gload16(kg + q * 1024, kd + q * 1024);
#pragma unroll
      for (int q = 0; q < 2; q++)
        gload16(vg + (size_t)q * 8 * (T_TOK * 2), vd + q * 1024);
    }

    const char* kb = (const char*)&Ks[cur][0];
    const char* vb = (const char*)&Vs[cur][0];

    // ---- S^T = K * Q^T : 4 key-subtiles x 4 d-steps
    f32x4 st[4] = {};
    __builtin_amdgcn_s_setprio(1);
#pragma unroll
    for (int t = 0; t < 4; t++)
#pragma unroll
      for (int ds = 0; ds < 4; ds++) {
        bf16x8 kf = *(const bf16x8*)(kb + (t * 16 + c) * 256 + ((ds * 64 + g * 16) ^ swz));
        st[t] = mfma16(kf, qf[ds], st[t]);
      }
    __builtin_amdgcn_s_setprio(0);

    // ---- mask + online softmax (q = c lane-local; keys j0+16t+4g+r)
    float p[16];
    float cmax = -1e30f;
    const int jb = i_row - j0 - 4 * g;  // i_row - j = jb - 16t - r
#pragma unroll
    for (int t = 0; t < 4; t++)
#pragma unroll
      for (int r = 0; r < 4; r++) {
        float s = st[t][r];
        // (j <= i_row) && (i_row - j <= WIN)  <=>  unsigned(i_row-j) <= WIN
        s = ((unsigned)(jb - 16 * t - r) <= WIN) ? s : -1e30f;
        p[t * 4 + r] = s;
        cmax = fmaxf(cmax, s);
      }
    cmax = fmaxf(cmax, __shfl_xor(cmax, 16));
    cmax = fmaxf(cmax, __shfl_xor(cmax, 32));

    // defer-max (T13, THR=8): skip O-rescale when max barely grows
    if (!__all(cmax <= mrun + 8.0f)) {
      const float mn = fmaxf(mrun, cmax);
      const float alpha = __expf(mrun - mn);
      lrun *= alpha;
#pragma unroll
      for (int m = 0; m < 8; m++) ot[m] *= alpha;
      mrun = mn;
    }
    float rs = 0.0f;
#pragma unroll
    for (int x = 0; x < 16; x++) {
      const float e_ = __expf(p[x] - mrun);
      p[x] = e_;
      rs += e_;
    }
    rs += __shfl_xor(rs, 16);
    rs += __shfl_xor(rs, 32);
    lrun += rs;

    // ---- P -> per-wave LDS (row=q=c, XOR-swizzled), re-read as B-fragments
#pragma unroll
    for (int t = 0; t < 4; t++) {
      bf16x4 pk;
      pk[0] = (__bf16)p[t * 4 + 0];
      pk[1] = (__bf16)p[t * 4 + 1];
      pk[2] = (__bf16)p[t * 4 + 2];
      pk[3] = (__bf16)p[t * 4 + 3];
      *(bf16x4*)(pw + c * 128 + ((t * 32 + g * 8) ^ swz)) = pk;
    }
    bf16x8 pf[2];
#pragma unroll
    for (int ks = 0; ks < 2; ks++)
      pf[ks] = *(const bf16x8*)(pw + c * 128 + ((ks * 64 + g * 16) ^ swz));

    // ---- O^T += V^T * P^T : 8 d-tiles x 2 key-subtiles
    __builtin_amdgcn_s_setprio(1);
#pragma unroll
    for (int m = 0; m < 8; m++)
#pragma unroll
      for (int ks = 0; ks < 2; ks++) {
        bf16x8 vf = *(const bf16x8*)(vb + (m * 16 + c) * 128 + ((ks * 64 + g * 16) ^ swz));
        ot[m] = mfma16(vf, pf[ks], ot[m]);
      }
    __builtin_amdgcn_s_setprio(0);

    cur ^= 1;
  }

  const float inv_l = 1.0f / lrun;
  __bf16* orow = attnO + (size_t)i_row * (NH * HD) + h * HD;
#pragma unroll
  for (int m = 0; m < 8; m++) {
    bf16x4 o4;
#pragma unroll
    for (int r = 0; r < 4; r++) o4[r] = (__bf16)(ot[m][r] * inv_l);
    *(bf16x4*)(orow + m * 16 + 4 * g) = o4;
  }
}

// ---------------- launcher ----------------
extern "C" void kernel_launch(void* const* d_in, const int* in_sizes, int n_in,
                              void* d_out, int out_size, void* d_ws, size_t ws_size,
                              hipStream_t stream) {
  (void)in_sizes; (void)n_in; (void)out_size; (void)ws_size;
  const float* hidden = (const float*)d_in[0];
  const int* positions = (const int*)d_in[1];
  const float* w_qkv = (const float*)d_in[2];
  const float* b_qkv = (const float*)d_in[3];
  const float* w_o = (const float*)d_in[4];
  float* out = (float*)d_out;

  char* ws = (char*)d_ws;
  __bf16* Hb = (__bf16*)ws;    ws += (size_t)T_TOK * HID * 2;        // 16 MB
  __bf16* Wqkvt = (__bf16*)ws; ws += (size_t)QKVO * HID * 2;         // 12 MB
  __bf16* Wot = (__bf16*)ws;   ws += (size_t)HID * HID * 2;          // 8 MB
  float* cosT = (float*)ws;    ws += (size_t)T_TOK * 64 * 4;         // 1 MB
  float* sinT = (float*)ws;    ws += (size_t)T_TOK * 64 * 4;         // 1 MB
  __bf16* qkv = (__bf16*)ws;   ws += (size_t)T_TOK * QKVO * 2;       // 24 MB
  __bf16* Qp = (__bf16*)ws;    ws += (size_t)NH * T_TOK * HD * 2;    // 16 MB
  __bf16* Kp = (__bf16*)ws;    ws += (size_t)NKV * T_TOK * HD * 2;   // 4 MB
  __bf16* Vt = (__bf16*)ws;    ws += (size_t)NKV * HD * T_TOK * 2;   // 4 MB
  __bf16* attnb = (__bf16*)ws; ws += (size_t)T_TOK * NH * HD * 2;    // 16 MB

  k_f32_to_bf16<<<T_TOK * HID / (256 * 8), 256, 0, stream>>>(hidden, Hb);
  k_transpose<<<(QKVO / 32) * (HID / 32), 256, 0, stream>>>(w_qkv, Wqkvt, HID, QKVO);
  k_transpose<<<(HID / 32) * (HID / 32), 256, 0, stream>>>(w_o, Wot, HID, HID);
  k_rope_tab<<<T_TOK, 64, 0, stream>>>(positions, cosT, sinT);
  k_gemm<true, __bf16><<<(T_TOK / 128) * (QKVO / 128), 256, 0, stream>>>(
      Hb, Wqkvt, b_qkv, qkv, T_TOK, QKVO, HID);
  k_rope_pack<<<dim3(T_TOK / 64, NH + 2 * NKV), 256, 0, stream>>>(
      qkv, cosT, sinT, Qp, Kp, Vt);
  k_attn<<<dim3(T_TOK / 128, NH), 512, 0, stream>>>(Qp, Kp, Vt, attnb);
  k_gemm<false, float><<<(T_TOK / 128) * (HID / 128), 256, 0, stream>>>(
      attnb, Wot, nullptr, out, T_TOK, HID, HID);
}